// Round 5
// baseline (525.022 us; speedup 1.0000x reference)
//
#include <hip/hip_runtime.h>
#include <stdint.h>

#define N_TOK 4096
#define DIM   2048
#define NH    16
#define HD    128
#define NW    (DIM * DIM)

using bf16x8 = __attribute__((ext_vector_type(8))) short;
using bf16x4 = __attribute__((ext_vector_type(4))) short;
using f32x4  = __attribute__((ext_vector_type(4))) float;
using u32x2  = __attribute__((ext_vector_type(2))) unsigned int;

#if __has_builtin(__builtin_amdgcn_exp2f)
#define EXP2(x) __builtin_amdgcn_exp2f(x)
#else
#define EXP2(x) exp2f(x)
#endif

__device__ inline unsigned short f2bf(float f) {
  union { float f; unsigned u; } v; v.f = f;
  unsigned r = v.u + 0x7FFFu + ((v.u >> 16) & 1u);
  return (unsigned short)(r >> 16);
}
__device__ inline float bf2f(unsigned short u) {
  union { unsigned u; float f; } v; v.u = ((unsigned)u) << 16; return v.f;
}
__device__ inline f32x4 mfma16(bf16x8 a, bf16x8 b, f32x4 c) {
  return __builtin_amdgcn_mfma_f32_16x16x32_bf16(a, b, c, 0, 0, 0);
}
// async global->LDS, 16B per lane; LDS dest = wave-uniform base + lane*16
__device__ inline void gll16(const unsigned short* g, unsigned short* l) {
  __builtin_amdgcn_global_load_lds(
      (const __attribute__((address_space(1))) void*)g,
      (__attribute__((address_space(3))) void*)l, 16, 0, 0);
}

// pack two f32 -> one u32 of 2x bf16 (RNE). No builtin on gfx950 (guide T12).
__device__ inline unsigned cvtpk_bf16(float lo, float hi) {
  unsigned r;
  asm("v_cvt_pk_bf16_f32 %0, %1, %2" : "=v"(r) : "v"(lo), "v"(hi));
  return r;
}

// permlane swaps (gfx950). ret.x = {A.lo16/32-groups..}, see call sites.
__device__ inline u32x2 pl32swap(unsigned a, unsigned b) {
#if __has_builtin(__builtin_amdgcn_permlane32_swap)
  return __builtin_amdgcn_permlane32_swap(a, b, false, false);
#else
  int lane = threadIdx.x & 63;
  unsigned as = (unsigned)__shfl_xor((int)a, 32);
  unsigned bs = (unsigned)__shfl_xor((int)b, 32);
  u32x2 r;
  r.x = (lane & 32) ? bs : a;   // {A.lo32, B.lo32}
  r.y = (lane & 32) ? b : as;   // {A.hi32, B.hi32}
  return r;
#endif
}
__device__ inline u32x2 pl16swap(unsigned a, unsigned b) {
#if __has_builtin(__builtin_amdgcn_permlane16_swap)
  return __builtin_amdgcn_permlane16_swap(a, b, false, false);
#else
  int lane = threadIdx.x & 63;
  unsigned as = (unsigned)__shfl_xor((int)a, 16);
  unsigned bs = (unsigned)__shfl_xor((int)b, 16);
  u32x2 r;
  r.x = (lane & 16) ? bs : a;   // {A.g0, B.g0, A.g2, B.g2} (16-lane groups)
  r.y = (lane & 16) ? b : as;   // {A.g1, B.g1, A.g3, B.g3}
  return r;
#endif
}

// fp32 -> bf16 convert, 8 elems/thread
__global__ __launch_bounds__(256)
void cvt_bf16(const float* __restrict__ src, unsigned short* __restrict__ dst, int n) {
  int i = blockIdx.x * 256 + threadIdx.x;
  if (i * 8 >= n) return;
  const float4* s = (const float4*)src + (size_t)i * 2;
  float4 a = s[0], b = s[1];
  bf16x8 o;
  o[0] = (short)f2bf(a.x); o[1] = (short)f2bf(a.y);
  o[2] = (short)f2bf(a.z); o[3] = (short)f2bf(a.w);
  o[4] = (short)f2bf(b.x); o[5] = (short)f2bf(b.y);
  o[6] = (short)f2bf(b.z); o[7] = (short)f2bf(b.w);
  *(bf16x8*)(dst + (size_t)i * 8) = o;
}

// C[4096,2048] = A[4096,2048] @ B[2048,2048]^T (+bias)*scale; all-bf16 inputs.
// T3 minimum-2-phase (guide §5.5): double-buffered LDS; STAGE(next tile)
// issued BEFORE compute(current), ONE __syncthreads (= vmcnt(0)+barrier) per
// K-step. Next tile's HBM latency hides under current tile's MFMAs, so the
// barrier's vmcnt(0) drain is nearly free (vs m97's stage-then-drain stall).
// OUT_MODE: 0 = bf16 row-major, 1 = fp32 row-major, 2 = bf16 transposed (Vt)
template<int OUT_MODE>
__global__ __launch_bounds__(256)
void gemm_bf16(const unsigned short* __restrict__ A, const unsigned short* __restrict__ B,
               const float* __restrict__ bias, void* __restrict__ out_, float scale) {
  __shared__ unsigned short Asl[2][128 * 32];
  __shared__ unsigned short Bsl[2][128 * 32];
  const int tid  = threadIdx.x;
  const int lane = tid & 63, w = tid >> 6;
  const int wy = w >> 1, wx = w & 1;
  const int lr = lane & 15, quad = lane >> 4;
  const int m0 = blockIdx.y * 128, n0 = blockIdx.x * 128;

  const f32x4 vzero = {0.f, 0.f, 0.f, 0.f};
  f32x4 acc[4][4];
#pragma unroll
  for (int i = 0; i < 4; ++i)
#pragma unroll
    for (int j = 0; j < 4; ++j) acc[i][j] = vzero;

  auto stage = [&](int buf, int k0) {
#pragma unroll
    for (int i = 0; i < 2; ++i) {
      int ch = tid + i * 256;            // 0..511 chunks of 16B
      int r = ch >> 2, cc = ch & 3;      // 128 rows x 4 chunks
      gll16(&A[(size_t)(m0 + r) * DIM + k0 + cc * 8], &Asl[buf][ch * 8]);
      gll16(&B[(size_t)(n0 + r) * DIM + k0 + cc * 8], &Bsl[buf][ch * 8]);
    }
  };

  constexpr int NKT = DIM / 32;  // 64 K-tiles
  stage(0, 0);
  __syncthreads();               // vmcnt(0) drain + barrier (prologue)

  int buf = 0;
  for (int t = 0; t < NKT; ++t) {
    if (t + 1 < NKT) stage(buf ^ 1, (t + 1) * 32);  // async, in flight under MFMAs

    bf16x8 af[4], bfv[4];
#pragma unroll
    for (int mb = 0; mb < 4; ++mb)
      af[mb] = *(const bf16x8*)&Asl[buf][(wy * 64 + mb * 16 + lr) * 32 + quad * 8];
#pragma unroll
    for (int nb = 0; nb < 4; ++nb)
      bfv[nb] = *(const bf16x8*)&Bsl[buf][(wx * 64 + nb * 16 + lr) * 32 + quad * 8];
#pragma unroll
    for (int mb = 0; mb < 4; ++mb)
#pragma unroll
      for (int nb = 0; nb < 4; ++nb)
        acc[mb][nb] = mfma16(af[mb], bfv[nb], acc[mb][nb]);

    __syncthreads();             // next tile landed; all reads of buf done
    buf ^= 1;
  }

#pragma unroll
  for (int mb = 0; mb < 4; ++mb)
#pragma unroll
    for (int nb = 0; nb < 4; ++nb) {
      int gn = n0 + wx * 64 + nb * 16 + lr;
      int gm_base = m0 + wy * 64 + mb * 16 + quad * 4;
      float bs = bias[gn];
      if constexpr (OUT_MODE == 2) {
        bf16x4 pk;
#pragma unroll
        for (int r = 0; r < 4; ++r) pk[r] = (short)f2bf((acc[mb][nb][r] + bs) * scale);
        *(bf16x4*)&((unsigned short*)out_)[(size_t)gn * N_TOK + gm_base] = pk;
      } else {
#pragma unroll
        for (int r = 0; r < 4; ++r) {
          float v = (acc[mb][nb][r] + bs) * scale;
          if constexpr (OUT_MODE == 1)
            ((float*)out_)[(size_t)(gm_base + r) * DIM + gn] = v;
          else
            ((unsigned short*)out_)[(size_t)(gm_base + r) * DIM + gn] = f2bf(v);
        }
      }
    }
}

// Flash attention, no-max softmax (scores bounded; exp2 domain folded into Q).
// R3 structure (best measured): mb=4 (64 q-rows/wave) for K/V-fragment reuse;
// grid = 256 blocks = 1/CU. Swapped QK^T (mfma(K,Q)) -> softmax fully in
// registers (cvt_pk + permlane). Single-buffered LDS, 2 barriers/iter,
// register prefetch of next K/V tile overlapping compute.
__global__ __launch_bounds__(256, 1)
void flash_attn(const unsigned short* __restrict__ Q,
                const unsigned short* __restrict__ K,
                const unsigned short* __restrict__ Vt,
                unsigned short* __restrict__ ctx) {
  constexpr int LDK = 136;  // K tile row stride (128+8)
  constexpr int LDV = 72;   // Vt tile row stride (64+8)
  constexpr int NT  = N_TOK / 64;
  __shared__ unsigned short Ksl[64 * LDK];
  __shared__ unsigned short VTsl[128 * LDV];

  const int tid  = threadIdx.x;
  const int lane = tid & 63, w = tid >> 6;
  const int lr = lane & 15, quad = lane >> 4;
  const int hoff = blockIdx.y * HD;
  const int q0   = blockIdx.x * 256;
  const int qw   = q0 + w * 64;

  // Q fragments; L2E/sqrt(128) already folded in at projection.
  // Layout [free=lr (q-row)][k=c*32+quad*8] = B-operand of swapped mfma(K,Q).
  bf16x8 qf[4][4];
#pragma unroll
  for (int mb = 0; mb < 4; ++mb)
#pragma unroll
    for (int c = 0; c < 4; ++c)
      qf[mb][c] = *(const bf16x8*)&Q[(size_t)(qw + mb * 16 + lr) * DIM + hoff + c * 32 + quad * 8];

  const f32x4 vzero = {0.f, 0.f, 0.f, 0.f};
  f32x4 o[4][8];
  float l_acc[4] = {0.f, 0.f, 0.f, 0.f};  // row-sum for q-row = lr (per mb)
#pragma unroll
  for (int mb = 0; mb < 4; ++mb)
#pragma unroll
    for (int nb = 0; nb < 8; ++nb) o[mb][nb] = vzero;

  bf16x8 kreg[4], vreg[4];
  auto load_tile = [&](int kt) {
    int kbase = kt * 64;
#pragma unroll
    for (int i = 0; i < 4; ++i) {
      int ch = tid + i * 256;
      kreg[i] = *(const bf16x8*)&K[(size_t)(kbase + (ch >> 4)) * DIM + hoff + (ch & 15) * 8];
      vreg[i] = *(const bf16x8*)&Vt[(size_t)(hoff + (ch >> 3)) * N_TOK + kbase + (ch & 7) * 8];
    }
  };
  load_tile(0);

  for (int kt = 0; kt < NT; ++kt) {
    __syncthreads();  // previous tile's LDS reads complete
#pragma unroll
    for (int i = 0; i < 4; ++i) {
      int ch = tid + i * 256;
      *(bf16x8*)&Ksl[(ch >> 4) * LDK + (ch & 15) * 8] = kreg[i];
      *(bf16x8*)&VTsl[(ch >> 3) * LDV + (ch & 7) * 8] = vreg[i];
    }
    __syncthreads();
    if (kt + 1 < NT) load_tile(kt + 1);  // global->reg prefetch under compute

    // S^T = K @ Q^T : lane holds S[q = mb*16+lr][key = nf*16 + quad*4 + r]
    f32x4 s[4][4];
#pragma unroll
    for (int mb = 0; mb < 4; ++mb)
#pragma unroll
      for (int nf = 0; nf < 4; ++nf) s[mb][nf] = vzero;
#pragma unroll
    for (int nf = 0; nf < 4; ++nf)
#pragma unroll
      for (int c = 0; c < 4; ++c) {
        bf16x8 kf = *(const bf16x8*)&Ksl[(nf * 16 + lr) * LDK + c * 32 + quad * 8];
#pragma unroll
        for (int mb = 0; mb < 4; ++mb) s[mb][nf] = mfma16(kf, qf[mb][c], s[mb][nf]);
      }

    // In-register softmax + redistribution into PV A-fragments.
    // Target word t of pf[mb][ki] (lane quad q) = keys ki*32 + q*8 + {2t,2t+1}
    //   = source lane quad (q&1)*2 + (t>>1), W[2ki + (q>>1)][t&1].
    bf16x8 pf[4][2];
#pragma unroll
    for (int mb = 0; mb < 4; ++mb) {
      unsigned W[4][2];
      float lp = 0.f;
#pragma unroll
      for (int nf = 0; nf < 4; ++nf) {
        float e0 = EXP2(s[mb][nf][0]);
        float e1 = EXP2(s[mb][nf][1]);
        float e2 = EXP2(s[mb][nf][2]);
        float e3 = EXP2(s[mb][nf][3]);
        lp += (e0 + e1) + (e2 + e3);
        W[nf][0] = cvtpk_bf16(e0, e1);
        W[nf][1] = cvtpk_bf16(e2, e3);
      }
      l_acc[mb] += lp;
#pragma unroll
      for (int ki = 0; ki < 2; ++ki) {
        u32x2 a0  = pl32swap(W[2 * ki][0], W[2 * ki + 1][0]);
        u32x2 t02 = pl16swap(a0.x, a0.y);   // (T0, T2)
        u32x2 a1  = pl32swap(W[2 * ki][1], W[2 * ki + 1][1]);
        u32x2 t13 = pl16swap(a1.x, a1.y);   // (T1, T3)
        union { unsigned u[4]; bf16x8 v; } pu;
        pu.u[0] = t02.x; pu.u[1] = t13.x; pu.u[2] = t02.y; pu.u[3] = t13.y;
        pf[mb][ki] = pu.v;
      }
    }

    // O += P @ V  (kf/vf reuse across 4 mb is the LDS-traffic win)
#pragma unroll
    for (int nb = 0; nb < 8; ++nb)
#pragma unroll
      for (int ki = 0; ki < 2; ++ki) {
        bf16x8 vf = *(const bf16x8*)&VTsl[(nb * 16 + lr) * LDV + ki * 32 + quad * 8];
#pragma unroll
        for (int mb = 0; mb < 4; ++mb) o[mb][nb] = mfma16(pf[mb][ki], vf, o[mb][nb]);
      }
  }

  // Row-sums live at q-row = lr; reduce the 4 quad-slices, then transpose
  // to q = quad*4+r via shfl for the store.
#pragma unroll
  for (int mb = 0; mb < 4; ++mb) {
    float t = l_acc[mb];
    t += __shfl_xor(t, 16);
    t += __shfl_xor(t, 32);
    l_acc[mb] = t;  // all lanes: L[mb][lr]
  }
#pragma unroll
  for (int mb = 0; mb < 4; ++mb)
#pragma unroll
    for (int r = 0; r < 4; ++r) {
      float Lr = __shfl(l_acc[mb], quad * 4 + r);  // L for q-row quad*4+r
      float inv = 1.0f / Lr;
      int gq = qw + mb * 16 + quad * 4 + r;
#pragma unroll
      for (int nb = 0; nb < 8; ++nb)
        ctx[(size_t)gq * DIM + hoff + nb * 16 + lr] = f2bf(o[mb][nb][r] * inv);
    }
}

extern "C" void kernel_launch(void* const* d_in, const int* in_sizes, int n_in,
                              void* d_out, int out_size, void* d_ws, size_t ws_size,
                              hipStream_t stream) {
  (void)in_sizes; (void)n_in; (void)out_size; (void)ws_size;
  const float* x  = (const float*)d_in[0];
  const float* Wq = (const float*)d_in[1];
  const float* bq = (const float*)d_in[2];
  const float* Wk = (const float*)d_in[3];
  const float* bk = (const float*)d_in[4];
  const float* Wv = (const float*)d_in[5];
  const float* bv = (const float*)d_in[6];
  const float* Wo = (const float*)d_in[7];
  const float* bo = (const float*)d_in[8];

  const size_t NE = (size_t)N_TOK * DIM;  // 8.4M
  unsigned short* xb  = (unsigned short*)d_ws;      // also reused as ctx later
  unsigned short* Wqb = xb + NE;
  unsigned short* Wkb = Wqb + NW;
  unsigned short* Wvb = Wkb + NW;
  unsigned short* Wob = Wvb + NW;
  unsigned short* Qb  = Wob + NW;
  unsigned short* Kb  = Qb + NE;
  unsigned short* Vtb = Kb + NE;   // total ~100.7 MB

  cvt_bf16<<<4096, 256, 0, stream>>>(x,  xb,  (int)NE);
  cvt_bf16<<<2048, 256, 0, stream>>>(Wq, Wqb, NW);
  cvt_bf16<<<2048, 256, 0, stream>>>(Wk, Wkb, NW);
  cvt_bf16<<<2048, 256, 0, stream>>>(Wv, Wvb, NW);
  cvt_bf16<<<2048, 256, 0, stream>>>(Wo, Wob, NW);

  dim3 gemm_grid(DIM / 128, N_TOK / 128);  // (16, 32)
  // fold softmax scale AND log2(e) into Q so scores are already in exp2 domain
  const float qscale = 1.4426950408889634f * 0.08838834764831845f;

  gemm_bf16<0><<<gemm_grid, 256, 0, stream>>>(xb, Wqb, bq, Qb, qscale);
  gemm_bf16<0><<<gemm_grid, 256, 0, stream>>>(xb, Wkb, bk, Kb, 1.0f);
  gemm_bf16<2><<<gemm_grid, 256, 0, stream>>>(xb, Wvb, bv, Vtb, 1.0f);

  unsigned short* ctxb = xb;  // x dead after V projection; reuse
  flash_attn<<<dim3(N_TOK / 256, NH), 256, 0, stream>>>(Qb, Kb, Vtb, ctxb);

  gemm_bf16<1><<<gemm_grid, 256, 0, stream>>>(ctxb, Wob, bo, (float*)d_out, 1.0f);
}

// Round 6
// 445.506 us; speedup vs baseline: 1.1785x; 1.1785x over previous
//
#include <hip/hip_runtime.h>
#include <stdint.h>

#define N_TOK 4096
#define DIM   2048
#define NH    16
#define HD    128
#define NW    (DIM * DIM)

using bf16x8 = __attribute__((ext_vector_type(8))) short;
using bf16x4 = __attribute__((ext_vector_type(4))) short;
using f32x4  = __attribute__((ext_vector_type(4))) float;
using u32x2  = __attribute__((ext_vector_type(2))) unsigned int;

#if __has_builtin(__builtin_amdgcn_exp2f)
#define EXP2(x) __builtin_amdgcn_exp2f(x)
#else
#define EXP2(x) exp2f(x)
#endif

__device__ inline unsigned short f2bf(float f) {
  union { float f; unsigned u; } v; v.f = f;
  unsigned r = v.u + 0x7FFFu + ((v.u >> 16) & 1u);
  return (unsigned short)(r >> 16);
}
__device__ inline float bf2f(unsigned short u) {
  union { unsigned u; float f; } v; v.u = ((unsigned)u) << 16; return v.f;
}
__device__ inline f32x4 mfma16(bf16x8 a, bf16x8 b, f32x4 c) {
  return __builtin_amdgcn_mfma_f32_16x16x32_bf16(a, b, c, 0, 0, 0);
}
// async global->LDS, 16B per lane; LDS dest = wave-uniform base + lane*16
__device__ inline void gll16(const unsigned short* g, unsigned short* l) {
  __builtin_amdgcn_global_load_lds(
      (const __attribute__((address_space(1))) void*)g,
      (__attribute__((address_space(3))) void*)l, 16, 0, 0);
}
// raw barrier with compiler-only memory fences (no waitcnt emitted)
__device__ inline void wgbar() {
  asm volatile("" ::: "memory");
  __builtin_amdgcn_s_barrier();
  asm volatile("" ::: "memory");
}

// pack two f32 -> one u32 of 2x bf16 (RNE). No builtin on gfx950 (guide T12).
__device__ inline unsigned cvtpk_bf16(float lo, float hi) {
  unsigned r;
  asm("v_cvt_pk_bf16_f32 %0, %1, %2" : "=v"(r) : "v"(lo), "v"(hi));
  return r;
}

// permlane swaps (gfx950). ret.x = {A.lo16/32-groups..}, see call sites.
__device__ inline u32x2 pl32swap(unsigned a, unsigned b) {
#if __has_builtin(__builtin_amdgcn_permlane32_swap)
  return __builtin_amdgcn_permlane32_swap(a, b, false, false);
#else
  int lane = threadIdx.x & 63;
  unsigned as = (unsigned)__shfl_xor((int)a, 32);
  unsigned bs = (unsigned)__shfl_xor((int)b, 32);
  u32x2 r;
  r.x = (lane & 32) ? bs : a;   // {A.lo32, B.lo32}
  r.y = (lane & 32) ? b : as;   // {A.hi32, B.hi32}
  return r;
#endif
}
__device__ inline u32x2 pl16swap(unsigned a, unsigned b) {
#if __has_builtin(__builtin_amdgcn_permlane16_swap)
  return __builtin_amdgcn_permlane16_swap(a, b, false, false);
#else
  int lane = threadIdx.x & 63;
  unsigned as = (unsigned)__shfl_xor((int)a, 16);
  unsigned bs = (unsigned)__shfl_xor((int)b, 16);
  u32x2 r;
  r.x = (lane & 16) ? bs : a;   // {A.g0, B.g0, A.g2, B.g2} (16-lane groups)
  r.y = (lane & 16) ? b : as;   // {A.g1, B.g1, A.g3, B.g3}
  return r;
#endif
}

// fp32 -> bf16 convert, 8 elems/thread
__global__ __launch_bounds__(256)
void cvt_bf16(const float* __restrict__ src, unsigned short* __restrict__ dst, int n) {
  int i = blockIdx.x * 256 + threadIdx.x;
  if (i * 8 >= n) return;
  const float4* s = (const float4*)src + (size_t)i * 2;
  float4 a = s[0], b = s[1];
  bf16x8 o;
  o[0] = (short)f2bf(a.x); o[1] = (short)f2bf(a.y);
  o[2] = (short)f2bf(a.z); o[3] = (short)f2bf(a.w);
  o[4] = (short)f2bf(b.x); o[5] = (short)f2bf(b.y);
  o[6] = (short)f2bf(b.z); o[7] = (short)f2bf(b.w);
  *(bf16x8*)(dst + (size_t)i * 8) = o;
}

// C[4096,2048] = A[4096,2048] @ B[2048,2048]^T (+bias)*scale; all-bf16 inputs.
// 8-phase-template port (guide S5.5 T2+T3+T4+T5, param variant BM=256 BN=128
// BK=64): 8 waves (4M x 2N, per-wave 64x64 = 4x4 frags), grid 16x16 = 256
// blocks = 1/CU. 3-deep LDS pipeline (144 KB), 2 phases/K-tile:
//   {ds_read 8 x b128 | stage 3 x global_load_lds -> s_barrier ->
//    16 MFMA under setprio -> s_barrier},  s_waitcnt vmcnt(6) ONCE per K-tile
// (never 0 in main loop: 6 loads of tile t+2 stay in flight across barriers).
// T2 swizzle: gll16 dest is linear (rule 21), so the XOR is applied to the
// GLOBAL source (gcc = cc ^ (row&7)) and to the ds_read slot; balances the
// 128B-row-stride frag reads across all 8 bank-quads (optimal 8-lane/quad).
// Hazards: stage(t+2) writes buf[(t+2)%3] == buf[(t-1)%3]; last readers of
// that slot finished >= 2 barriers upstream. vmcnt(6)+barrier at ph1 end =>
// every wave's tile-t+1 loads (its 6 oldest) complete before any wave reads
// tile t+1. Epilogue peels last 2 tiles with vmcnt(0).
// OUT_MODE: 0 = bf16 row-major, 1 = fp32 row-major, 2 = bf16 transposed (Vt)
template<int OUT_MODE>
__global__ __launch_bounds__(512, 2)
void gemm_bf16(const unsigned short* __restrict__ A, const unsigned short* __restrict__ B,
               const float* __restrict__ bias, void* __restrict__ out_, float scale) {
  constexpr int BM = 256, BN = 128, BK = 64;
  constexpr int NKT = DIM / BK;              // 32
  __shared__ unsigned short Asl[3][BM * BK]; // 3 x 32 KB
  __shared__ unsigned short Bsl[3][BN * BK]; // 3 x 16 KB  (total 144 KB)

  const int tid  = threadIdx.x;
  const int lane = tid & 63;
  const int w    = tid >> 6;
  const int wm = w >> 1, wn = w & 1;         // 4M x 2N
  const int lr = lane & 15, quad = lane >> 4;
  const int m0 = blockIdx.y * BM, n0 = blockIdx.x * BN;

  const f32x4 vzero = {0.f, 0.f, 0.f, 0.f};
  f32x4 acc[4][4];
#pragma unroll
  for (int i = 0; i < 4; ++i)
#pragma unroll
    for (int j = 0; j < 4; ++j) acc[i][j] = vzero;

  // staging descriptors: A = 4 chunks/thread, B = 2 chunks/thread (16B each).
  // LDS write linear at ch*16B; global source col pre-swizzled (m173).
  size_t asrc[4]; int aldst[4];
  size_t bsrc[2]; int bldst[2];
#pragma unroll
  for (int i = 0; i < 4; ++i) {
    int ch = tid + i * 512;                  // 0..2047
    int row = ch >> 3, cc = ch & 7;
    int gcc = cc ^ (row & 7);
    asrc[i]  = (size_t)(m0 + row) * DIM + gcc * 8;
    aldst[i] = ch * 8;
  }
#pragma unroll
  for (int i = 0; i < 2; ++i) {
    int ch = tid + i * 512;                  // 0..1023
    int row = ch >> 3, cc = ch & 7;
    int gcc = cc ^ (row & 7);
    bsrc[i]  = (size_t)(n0 + row) * DIM + gcc * 8;
    bldst[i] = ch * 8;
  }
  // half 0: A0, A1, B0 ; half 1: A2, A3, B1  (3 gll16 each)
  auto stage_half = [&](int buf, int k0, int half) {
    int a0 = half * 2;
    gll16(&A[asrc[a0] + k0],     &Asl[buf][aldst[a0]]);
    gll16(&A[asrc[a0 + 1] + k0], &Asl[buf][aldst[a0 + 1]]);
    gll16(&B[bsrc[half] + k0],   &Bsl[buf][bldst[half]]);
  };

  auto lda = [&](int buf, int ks, bf16x8* af) {
#pragma unroll
    for (int mb = 0; mb < 4; ++mb) {
      int row  = wm * 64 + mb * 16 + lr;
      int slot = (ks * 4 + quad) ^ (row & 7);
      af[mb] = *(const bf16x8*)&Asl[buf][row * 64 + slot * 8];
    }
  };
  auto ldb = [&](int buf, int ks, bf16x8* bfv) {
#pragma unroll
    for (int nb = 0; nb < 4; ++nb) {
      int row  = wn * 64 + nb * 16 + lr;
      int slot = (ks * 4 + quad) ^ (row & 7);
      bfv[nb] = *(const bf16x8*)&Bsl[buf][row * 64 + slot * 8];
    }
  };
  auto mm = [&](bf16x8* af, bf16x8* bfv) {
    __builtin_amdgcn_s_setprio(1);
#pragma unroll
    for (int mb = 0; mb < 4; ++mb)
#pragma unroll
      for (int nb = 0; nb < 4; ++nb)
        acc[mb][nb] = mfma16(af[mb], bfv[nb], acc[mb][nb]);
    __builtin_amdgcn_s_setprio(0);
  };

  // ---- prologue: stage tiles 0 and 1; wait tile 0 (6 in flight stays) ----
  stage_half(0, 0, 0);  stage_half(0, 0, 1);
  stage_half(1, BK, 0); stage_half(1, BK, 1);
  asm volatile("s_waitcnt vmcnt(6)" ::: "memory");
  wgbar();

  // ---- main loop: tiles 0..NKT-3, staging t+2, vmcnt(6) per K-tile ----
  for (int t = 0; t < NKT - 2; ++t) {
    const int buf = t % 3, sb = (t + 2) % 3, sk = (t + 2) * BK;
    bf16x8 af[4], bfv[4];
    // phase 0 (k-slice 0)
    lda(buf, 0, af); ldb(buf, 0, bfv);
    stage_half(sb, sk, 0);
    wgbar();
    mm(af, bfv);
    wgbar();
    // phase 1 (k-slice 1)
    lda(buf, 1, af); ldb(buf, 1, bfv);
    stage_half(sb, sk, 1);
    asm volatile("s_waitcnt vmcnt(6)" ::: "memory");  // tile t+1 landed
    wgbar();
    mm(af, bfv);
    wgbar();
  }
  // ---- epilogue tile NKT-2: no staging; drain tile NKT-1 ----
  {
    const int buf = (NKT - 2) % 3;
    bf16x8 af[4], bfv[4];
    lda(buf, 0, af); ldb(buf, 0, bfv);
    wgbar(); mm(af, bfv); wgbar();
    lda(buf, 1, af); ldb(buf, 1, bfv);
    asm volatile("s_waitcnt vmcnt(0)" ::: "memory");  // tile NKT-1 landed
    wgbar(); mm(af, bfv); wgbar();
  }
  // ---- epilogue tile NKT-1: pure compute ----
  {
    const int buf = (NKT - 1) % 3;
    bf16x8 af[4], bfv[4];
    lda(buf, 0, af); ldb(buf, 0, bfv);
    mm(af, bfv);
    lda(buf, 1, af); ldb(buf, 1, bfv);
    mm(af, bfv);
  }

  // ---- C write ----
#pragma unroll
  for (int mb = 0; mb < 4; ++mb)
#pragma unroll
    for (int nb = 0; nb < 4; ++nb) {
      int gn = n0 + wn * 64 + nb * 16 + lr;
      int gm_base = m0 + wm * 64 + mb * 16 + quad * 4;
      float bs = bias[gn];
      if constexpr (OUT_MODE == 2) {
        bf16x4 pk;
#pragma unroll
        for (int r = 0; r < 4; ++r) pk[r] = (short)f2bf((acc[mb][nb][r] + bs) * scale);
        *(bf16x4*)&((unsigned short*)out_)[(size_t)gn * N_TOK + gm_base] = pk;
      } else {
#pragma unroll
        for (int r = 0; r < 4; ++r) {
          float v = (acc[mb][nb][r] + bs) * scale;
          if constexpr (OUT_MODE == 1)
            ((float*)out_)[(size_t)(gm_base + r) * DIM + gn] = v;
          else
            ((unsigned short*)out_)[(size_t)(gm_base + r) * DIM + gn] = f2bf(v);
        }
      }
    }
}

// Flash attention, no-max softmax (scores bounded; exp2 domain folded into Q).
// R3 structure (best measured): mb=4 (64 q-rows/wave) for K/V-fragment reuse;
// grid = 256 blocks = 1/CU. Swapped QK^T (mfma(K,Q)) -> softmax fully in
// registers (cvt_pk + permlane). Single-buffered LDS, 2 barriers/iter,
// register prefetch of next K/V tile overlapping compute.
__global__ __launch_bounds__(256, 1)
void flash_attn(const unsigned short* __restrict__ Q,
                const unsigned short* __restrict__ K,
                const unsigned short* __restrict__ Vt,
                unsigned short* __restrict__ ctx) {
  constexpr int LDK = 136;  // K tile row stride (128+8)
  constexpr int LDV = 72;   // Vt tile row stride (64+8)
  constexpr int NT  = N_TOK / 64;
  __shared__ unsigned short Ksl[64 * LDK];
  __shared__ unsigned short VTsl[128 * LDV];

  const int tid  = threadIdx.x;
  const int lane = tid & 63, w = tid >> 6;
  const int lr = lane & 15, quad = lane >> 4;
  const int hoff = blockIdx.y * HD;
  const int q0   = blockIdx.x * 256;
  const int qw   = q0 + w * 64;

  // Q fragments; L2E/sqrt(128) already folded in at projection.
  // Layout [free=lr (q-row)][k=c*32+quad*8] = B-operand of swapped mfma(K,Q).
  bf16x8 qf[4][4];
#pragma unroll
  for (int mb = 0; mb < 4; ++mb)
#pragma unroll
    for (int c = 0; c < 4; ++c)
      qf[mb][c] = *(const bf16x8*)&Q[(size_t)(qw + mb * 16 + lr) * DIM + hoff + c * 32 + quad * 8];

  const f32x4 vzero = {0.f, 0.f, 0.f, 0.f};
  f32x4 o[4][8];
  float l_acc[4] = {0.f, 0.f, 0.f, 0.f};  // row-sum for q-row = lr (per mb)
#pragma unroll
  for (int mb = 0; mb < 4; ++mb)
#pragma unroll
    for (int nb = 0; nb < 8; ++nb) o[mb][nb] = vzero;

  bf16x8 kreg[4], vreg[4];
  auto load_tile = [&](int kt) {
    int kbase = kt * 64;
#pragma unroll
    for (int i = 0; i < 4; ++i) {
      int ch = tid + i * 256;
      kreg[i] = *(const bf16x8*)&K[(size_t)(kbase + (ch >> 4)) * DIM + hoff + (ch & 15) * 8];
      vreg[i] = *(const bf16x8*)&Vt[(size_t)(hoff + (ch >> 3)) * N_TOK + kbase + (ch & 7) * 8];
    }
  };
  load_tile(0);

  for (int kt = 0; kt < NT; ++kt) {
    __syncthreads();  // previous tile's LDS reads complete
#pragma unroll
    for (int i = 0; i < 4; ++i) {
      int ch = tid + i * 256;
      *(bf16x8*)&Ksl[(ch >> 4) * LDK + (ch & 15) * 8] = kreg[i];
      *(bf16x8*)&VTsl[(ch >> 3) * LDV + (ch & 7) * 8] = vreg[i];
    }
    __syncthreads();
    if (kt + 1 < NT) load_tile(kt + 1);  // global->reg prefetch under compute

    // S^T = K @ Q^T : lane holds S[q = mb*16+lr][key = nf*16 + quad*4 + r]
    f32x4 s[4][4];
#pragma unroll
    for (int mb = 0; mb < 4; ++mb)
#pragma unroll
      for (int nf = 0; nf < 4; ++nf) s[mb][nf] = vzero;
#pragma unroll
    for (int nf = 0; nf < 4; ++nf)
#pragma unroll
      for (int c = 0; c < 4; ++c) {
        bf16x8 kf = *(const bf16x8*)&Ksl[(nf * 16 + lr) * LDK + c * 32 + quad * 8];
#pragma unroll
        for (int mb = 0; mb < 4; ++mb) s[mb][nf] = mfma16(kf, qf[mb][c], s[mb][nf]);
      }

    // In-register softmax + redistribution into PV A-fragments.
    // Target word t of pf[mb][ki] (lane quad q) = keys ki*32 + q*8 + {2t,2t+1}
    //   = source lane quad (q&1)*2 + (t>>1), W[2ki + (q>>1)][t&1].
    bf16x8 pf[4][2];
#pragma unroll
    for (int mb = 0; mb < 4; ++mb) {
      unsigned W[4][2];
      float lp = 0.f;
#pragma unroll
      for (int nf = 0; nf < 4; ++nf) {
        float e0 = EXP2(s[mb][nf][0]);
        float e1 = EXP2(s[mb][nf][1]);
        float e2 = EXP2(s[mb][nf][2]);
        float e3 = EXP2(s[mb][nf][3]);
        lp += (e0 + e1) + (e2 + e3);
        W[nf][0] = cvtpk_bf16(e0, e1);
        W[nf][1] = cvtpk_bf16(e2, e3);
      }
      l_acc[mb] += lp;
#pragma unroll
      for (int ki = 0; ki < 2; ++ki) {
        u32x2 a0  = pl32swap(W[2 * ki][0], W[2 * ki + 1][0]);
        u32x2 t02 = pl16swap(a0.x, a0.y);   // (T0, T2)
        u32x2 a1  = pl32swap(W[2 * ki][1], W[2 * ki + 1][1]);
        u32x2 t13 = pl16swap(a1.x, a1.y);   // (T1, T3)
        union { unsigned u[4]; bf16x8 v; } pu;
        pu.u[0] = t02.x; pu.u[1] = t13.x; pu.u[2] = t02.y; pu.u[3] = t13.y;
        pf[mb][ki] = pu.v;
      }
    }

    // O += P @ V  (kf/vf reuse across 4 mb is the LDS-traffic win)
#pragma unroll
    for (int nb = 0; nb < 8; ++nb)
#pragma unroll
      for (int ki = 0; ki < 2; ++ki) {
        bf16x8 vf = *(const bf16x8*)&VTsl[(nb * 16 + lr) * LDV + ki * 32 + quad * 8];
#pragma unroll
        for (int mb = 0; mb < 4; ++mb) o[mb][nb] = mfma16(pf[mb][ki], vf, o[mb][nb]);
      }
  }

  // Row-sums live at q-row = lr; reduce the 4 quad-slices, then transpose
  // to q = quad*4+r via shfl for the store.
#pragma unroll
  for (int mb = 0; mb < 4; ++mb) {
    float t = l_acc[mb];
    t += __shfl_xor(t, 16);
    t += __shfl_xor(t, 32);
    l_acc[mb] = t;  // all lanes: L[mb][lr]
  }
#pragma unroll
  for (int mb = 0; mb < 4; ++mb)
#pragma unroll
    for (int r = 0; r < 4; ++r) {
      float Lr = __shfl(l_acc[mb], quad * 4 + r);  // L for q-row quad*4+r
      float inv = 1.0f / Lr;
      int gq = qw + mb * 16 + quad * 4 + r;
#pragma unroll
      for (int nb = 0; nb < 8; ++nb)
        ctx[(size_t)gq * DIM + hoff + nb * 16 + lr] = f2bf(o[mb][nb][r] * inv);
    }
}

extern "C" void kernel_launch(void* const* d_in, const int* in_sizes, int n_in,
                              void* d_out, int out_size, void* d_ws, size_t ws_size,
                              hipStream_t stream) {
  (void)in_sizes; (void)n_in; (void)out_size; (void)ws_size;
  const float* x  = (const float*)d_in[0];
  const float* Wq = (const float*)d_in[1];
  const float* bq = (const float*)d_in[2];
  const float* Wk = (const float*)d_in[3];
  const float* bk = (const float*)d_in[4];
  const float* Wv = (const float*)d_in[5];
  const float* bv = (const float*)d_in[6];
  const float* Wo = (const float*)d_in[7];
  const float* bo = (const float*)d_in[8];

  const size_t NE = (size_t)N_TOK * DIM;  // 8.4M
  unsigned short* xb  = (unsigned short*)d_ws;      // also reused as ctx later
  unsigned short* Wqb = xb + NE;
  unsigned short* Wkb = Wqb + NW;
  unsigned short* Wvb = Wkb + NW;
  unsigned short* Wob = Wvb + NW;
  unsigned short* Qb  = Wob + NW;
  unsigned short* Kb  = Qb + NE;
  unsigned short* Vtb = Kb + NE;   // total ~100.7 MB

  cvt_bf16<<<4096, 256, 0, stream>>>(x,  xb,  (int)NE);
  cvt_bf16<<<2048, 256, 0, stream>>>(Wq, Wqb, NW);
  cvt_bf16<<<2048, 256, 0, stream>>>(Wk, Wkb, NW);
  cvt_bf16<<<2048, 256, 0, stream>>>(Wv, Wvb, NW);
  cvt_bf16<<<2048, 256, 0, stream>>>(Wo, Wob, NW);

  dim3 gemm_grid(DIM / 128, N_TOK / 256);  // (16, 16) = 256 blocks = 1/CU
  // fold softmax scale AND log2(e) into Q so scores are already in exp2 domain
  const float qscale = 1.4426950408889634f * 0.08838834764831845f;

  gemm_bf16<0><<<gemm_grid, 512, 0, stream>>>(xb, Wqb, bq, Qb, qscale);
  gemm_bf16<0><<<gemm_grid, 512, 0, stream>>>(xb, Wkb, bk, Kb, 1.0f);
  gemm_bf16<2><<<gemm_grid, 512, 0, stream>>>(xb, Wvb, bv, Vtb, 1.0f);

  unsigned short* ctxb = xb;  // x dead after V projection; reuse
  flash_attn<<<dim3(N_TOK / 256, NH), 256, 0, stream>>>(Qb, Kb, Vtb, ctxb);

  gemm_bf16<1><<<gemm_grid, 512, 0, stream>>>(ctxb, Wob, bo, (float*)d_out, 1.0f);
}

// Round 7
// 442.946 us; speedup vs baseline: 1.1853x; 1.0058x over previous
//
#include <hip/hip_runtime.h>
#include <stdint.h>

#define N_TOK 4096
#define DIM   2048
#define NH    16
#define HD    128
#define NW    (DIM * DIM)

using bf16x8 = __attribute__((ext_vector_type(8))) short;
using bf16x4 = __attribute__((ext_vector_type(4))) short;
using f32x4  = __attribute__((ext_vector_type(4))) float;
using u32x2  = __attribute__((ext_vector_type(2))) unsigned int;

#if __has_builtin(__builtin_amdgcn_exp2f)
#define EXP2(x) __builtin_amdgcn_exp2f(x)
#else
#define EXP2(x) exp2f(x)
#endif

__device__ inline unsigned short f2bf(float f) {
  union { float f; unsigned u; } v; v.f = f;
  unsigned r = v.u + 0x7FFFu + ((v.u >> 16) & 1u);
  return (unsigned short)(r >> 16);
}
__device__ inline float bf2f(unsigned short u) {
  union { unsigned u; float f; } v; v.u = ((unsigned)u) << 16; return v.f;
}
__device__ inline f32x4 mfma16(bf16x8 a, bf16x8 b, f32x4 c) {
  return __builtin_amdgcn_mfma_f32_16x16x32_bf16(a, b, c, 0, 0, 0);
}
// async global->LDS, 16B per lane; LDS dest = wave-uniform base + lane*16
__device__ inline void gll16(const unsigned short* g, unsigned short* l) {
  __builtin_amdgcn_global_load_lds(
      (const __attribute__((address_space(1))) void*)g,
      (__attribute__((address_space(3))) void*)l, 16, 0, 0);
}
// raw barrier with compiler-only memory fences (no waitcnt emitted)
__device__ inline void wgbar() {
  asm volatile("" ::: "memory");
  __builtin_amdgcn_s_barrier();
  asm volatile("" ::: "memory");
}

// pack two f32 -> one u32 of 2x bf16 (RNE). No builtin on gfx950 (guide T12).
__device__ inline unsigned cvtpk_bf16(float lo, float hi) {
  unsigned r;
  asm("v_cvt_pk_bf16_f32 %0, %1, %2" : "=v"(r) : "v"(lo), "v"(hi));
  return r;
}

// permlane swaps (gfx950). ret.x = {A.lo16/32-groups..}, see call sites.
__device__ inline u32x2 pl32swap(unsigned a, unsigned b) {
#if __has_builtin(__builtin_amdgcn_permlane32_swap)
  return __builtin_amdgcn_permlane32_swap(a, b, false, false);
#else
  int lane = threadIdx.x & 63;
  unsigned as = (unsigned)__shfl_xor((int)a, 32);
  unsigned bs = (unsigned)__shfl_xor((int)b, 32);
  u32x2 r;
  r.x = (lane & 32) ? bs : a;   // {A.lo32, B.lo32}
  r.y = (lane & 32) ? b : as;   // {A.hi32, B.hi32}
  return r;
#endif
}
__device__ inline u32x2 pl16swap(unsigned a, unsigned b) {
#if __has_builtin(__builtin_amdgcn_permlane16_swap)
  return __builtin_amdgcn_permlane16_swap(a, b, false, false);
#else
  int lane = threadIdx.x & 63;
  unsigned as = (unsigned)__shfl_xor((int)a, 16);
  unsigned bs = (unsigned)__shfl_xor((int)b, 16);
  u32x2 r;
  r.x = (lane & 16) ? bs : a;   // {A.g0, B.g0, A.g2, B.g2} (16-lane groups)
  r.y = (lane & 16) ? b : as;   // {A.g1, B.g1, A.g3, B.g3}
  return r;
#endif
}

// fp32 -> bf16 convert, 8 elems/thread
__global__ __launch_bounds__(256)
void cvt_bf16(const float* __restrict__ src, unsigned short* __restrict__ dst, int n) {
  int i = blockIdx.x * 256 + threadIdx.x;
  if (i * 8 >= n) return;
  const float4* s = (const float4*)src + (size_t)i * 2;
  float4 a = s[0], b = s[1];
  bf16x8 o;
  o[0] = (short)f2bf(a.x); o[1] = (short)f2bf(a.y);
  o[2] = (short)f2bf(a.z); o[3] = (short)f2bf(a.w);
  o[4] = (short)f2bf(b.x); o[5] = (short)f2bf(b.y);
  o[6] = (short)f2bf(b.z); o[7] = (short)f2bf(b.w);
  *(bf16x8*)(dst + (size_t)i * 8) = o;
}

// C[4096,2048] = A[4096,2048] @ B[2048,2048]^T (+bias)*scale; all-bf16 inputs.
// 8-phase structure (R6) + T1 chunked XCD swizzle (R7).
// R6 post-mortem: 61 us/GEMM == 384 MB panel-refetch / 6.3 TB/s -> HBM-bound.
// Flat bid%8 XCD round-robin makes each XCD's 32 co-resident blocks touch ALL
// 16 A panels (16.8 MB >> 4 MB L2). Remap nb=(bid&7)*32+(bid>>3) (bijective,
// 256%8==0), m-major decomp: each XCD = 2 m-rows x 16 n-blocks -> shared A =
// 2 MB (L2-fits), per-K-tile B window ~256 KB -> L2 serves the re-reads.
// Pipeline: 3-deep LDS (144 KB), 2 phases/K-tile, s_waitcnt vmcnt(6) once per
// K-tile (6 loads of tile t+2 stay in flight across barriers), MFMA under
// setprio. T2 swizzle via pre-swizzled GLOBAL source col (rule 21) + XOR'd
// ds_read slot. Hazards: stage(t+2) writes buf[(t+2)%3]=buf[(t-1)%3], last
// read >=2 barriers upstream; vmcnt(6)+barrier orders tile t+1 loads before
// any wave reads them. Epilogue peels last 2 tiles (vmcnt(0)).
// OUT_MODE: 0 = bf16 row-major, 1 = fp32 row-major, 2 = bf16 transposed (Vt)
template<int OUT_MODE>
__global__ __launch_bounds__(512, 2)
void gemm_bf16(const unsigned short* __restrict__ A, const unsigned short* __restrict__ B,
               const float* __restrict__ bias, void* __restrict__ out_, float scale) {
  constexpr int BM = 256, BN = 128, BK = 64;
  constexpr int NKT = DIM / BK;              // 32
  __shared__ unsigned short Asl[3][BM * BK]; // 3 x 32 KB
  __shared__ unsigned short Bsl[3][BN * BK]; // 3 x 16 KB  (total 144 KB)

  const int tid  = threadIdx.x;
  const int lane = tid & 63;
  const int w    = tid >> 6;
  const int wm = w >> 1, wn = w & 1;         // 4M x 2N
  const int lr = lane & 15, quad = lane >> 4;

  // T1 chunked XCD swizzle: contiguous 32-block chunk per XCD, m-major.
  const int bid = blockIdx.x;                // 0..255
  const int nb  = (bid & 7) * 32 + (bid >> 3);
  const int m0  = (nb >> 4) * BM;            // 16 m-blocks
  const int n0  = (nb & 15) * BN;            // 16 n-blocks

  const f32x4 vzero = {0.f, 0.f, 0.f, 0.f};
  f32x4 acc[4][4];
#pragma unroll
  for (int i = 0; i < 4; ++i)
#pragma unroll
    for (int j = 0; j < 4; ++j) acc[i][j] = vzero;

  // staging descriptors: A = 4 chunks/thread, B = 2 chunks/thread (16B each).
  // LDS write linear at ch*16B; global source col pre-swizzled (m173).
  size_t asrc[4]; int aldst[4];
  size_t bsrc[2]; int bldst[2];
#pragma unroll
  for (int i = 0; i < 4; ++i) {
    int ch = tid + i * 512;                  // 0..2047
    int row = ch >> 3, cc = ch & 7;
    int gcc = cc ^ (row & 7);
    asrc[i]  = (size_t)(m0 + row) * DIM + gcc * 8;
    aldst[i] = ch * 8;
  }
#pragma unroll
  for (int i = 0; i < 2; ++i) {
    int ch = tid + i * 512;                  // 0..1023
    int row = ch >> 3, cc = ch & 7;
    int gcc = cc ^ (row & 7);
    bsrc[i]  = (size_t)(n0 + row) * DIM + gcc * 8;
    bldst[i] = ch * 8;
  }
  // half 0: A0, A1, B0 ; half 1: A2, A3, B1  (3 gll16 each)
  auto stage_half = [&](int buf, int k0, int half) {
    int a0 = half * 2;
    gll16(&A[asrc[a0] + k0],     &Asl[buf][aldst[a0]]);
    gll16(&A[asrc[a0 + 1] + k0], &Asl[buf][aldst[a0 + 1]]);
    gll16(&B[bsrc[half] + k0],   &Bsl[buf][bldst[half]]);
  };

  auto lda = [&](int buf, int ks, bf16x8* af) {
#pragma unroll
    for (int mb = 0; mb < 4; ++mb) {
      int row  = wm * 64 + mb * 16 + lr;
      int slot = (ks * 4 + quad) ^ (row & 7);
      af[mb] = *(const bf16x8*)&Asl[buf][row * 64 + slot * 8];
    }
  };
  auto ldb = [&](int buf, int ks, bf16x8* bfv) {
#pragma unroll
    for (int nb2 = 0; nb2 < 4; ++nb2) {
      int row  = wn * 64 + nb2 * 16 + lr;
      int slot = (ks * 4 + quad) ^ (row & 7);
      bfv[nb2] = *(const bf16x8*)&Bsl[buf][row * 64 + slot * 8];
    }
  };
  auto mm = [&](bf16x8* af, bf16x8* bfv) {
    __builtin_amdgcn_s_setprio(1);
#pragma unroll
    for (int mb = 0; mb < 4; ++mb)
#pragma unroll
      for (int nb2 = 0; nb2 < 4; ++nb2)
        acc[mb][nb2] = mfma16(af[mb], bfv[nb2], acc[mb][nb2]);
    __builtin_amdgcn_s_setprio(0);
  };

  // ---- prologue: stage tiles 0 and 1; wait tile 0 (6 in flight stays) ----
  stage_half(0, 0, 0);  stage_half(0, 0, 1);
  stage_half(1, BK, 0); stage_half(1, BK, 1);
  asm volatile("s_waitcnt vmcnt(6)" ::: "memory");
  wgbar();

  // ---- main loop: tiles 0..NKT-3, staging t+2, vmcnt(6) per K-tile ----
  for (int t = 0; t < NKT - 2; ++t) {
    const int buf = t % 3, sb = (t + 2) % 3, sk = (t + 2) * BK;
    bf16x8 af[4], bfv[4];
    // phase 0 (k-slice 0)
    lda(buf, 0, af); ldb(buf, 0, bfv);
    stage_half(sb, sk, 0);
    wgbar();
    mm(af, bfv);
    wgbar();
    // phase 1 (k-slice 1)
    lda(buf, 1, af); ldb(buf, 1, bfv);
    stage_half(sb, sk, 1);
    asm volatile("s_waitcnt vmcnt(6)" ::: "memory");  // tile t+1 landed
    wgbar();
    mm(af, bfv);
    wgbar();
  }
  // ---- epilogue tile NKT-2: no staging; drain tile NKT-1 ----
  {
    const int buf = (NKT - 2) % 3;
    bf16x8 af[4], bfv[4];
    lda(buf, 0, af); ldb(buf, 0, bfv);
    wgbar(); mm(af, bfv); wgbar();
    lda(buf, 1, af); ldb(buf, 1, bfv);
    asm volatile("s_waitcnt vmcnt(0)" ::: "memory");  // tile NKT-1 landed
    wgbar(); mm(af, bfv); wgbar();
  }
  // ---- epilogue tile NKT-1: pure compute ----
  {
    const int buf = (NKT - 1) % 3;
    bf16x8 af[4], bfv[4];
    lda(buf, 0, af); ldb(buf, 0, bfv);
    mm(af, bfv);
    lda(buf, 1, af); ldb(buf, 1, bfv);
    mm(af, bfv);
  }

  // ---- C write ----
#pragma unroll
  for (int mb = 0; mb < 4; ++mb)
#pragma unroll
    for (int nb2 = 0; nb2 < 4; ++nb2) {
      int gn = n0 + wn * 64 + nb2 * 16 + lr;
      int gm_base = m0 + wm * 64 + mb * 16 + quad * 4;
      float bs = bias[gn];
      if constexpr (OUT_MODE == 2) {
        bf16x4 pk;
#pragma unroll
        for (int r = 0; r < 4; ++r) pk[r] = (short)f2bf((acc[mb][nb2][r] + bs) * scale);
        *(bf16x4*)&((unsigned short*)out_)[(size_t)gn * N_TOK + gm_base] = pk;
      } else {
#pragma unroll
        for (int r = 0; r < 4; ++r) {
          float v = (acc[mb][nb2][r] + bs) * scale;
          if constexpr (OUT_MODE == 1)
            ((float*)out_)[(size_t)(gm_base + r) * DIM + gn] = v;
          else
            ((unsigned short*)out_)[(size_t)(gm_base + r) * DIM + gn] = f2bf(v);
        }
      }
    }
}

// Flash attention, no-max softmax (scores bounded; exp2 domain folded into Q).
// R3 structure (best measured): mb=4 (64 q-rows/wave) for K/V-fragment reuse;
// grid = 256 blocks = 1/CU. Swapped QK^T (mfma(K,Q)) -> softmax fully in
// registers (cvt_pk + permlane). Single-buffered LDS, 2 barriers/iter,
// register prefetch of next K/V tile overlapping compute.
__global__ __launch_bounds__(256, 1)
void flash_attn(const unsigned short* __restrict__ Q,
                const unsigned short* __restrict__ K,
                const unsigned short* __restrict__ Vt,
                unsigned short* __restrict__ ctx) {
  constexpr int LDK = 136;  // K tile row stride (128+8)
  constexpr int LDV = 72;   // Vt tile row stride (64+8)
  constexpr int NT  = N_TOK / 64;
  __shared__ unsigned short Ksl[64 * LDK];
  __shared__ unsigned short VTsl[128 * LDV];

  const int tid  = threadIdx.x;
  const int lane = tid & 63, w = tid >> 6;
  const int lr = lane & 15, quad = lane >> 4;
  const int hoff = blockIdx.y * HD;
  const int q0   = blockIdx.x * 256;
  const int qw   = q0 + w * 64;

  // Q fragments; L2E/sqrt(128) already folded in at projection.
  // Layout [free=lr (q-row)][k=c*32+quad*8] = B-operand of swapped mfma(K,Q).
  bf16x8 qf[4][4];
#pragma unroll
  for (int mb = 0; mb < 4; ++mb)
#pragma unroll
    for (int c = 0; c < 4; ++c)
      qf[mb][c] = *(const bf16x8*)&Q[(size_t)(qw + mb * 16 + lr) * DIM + hoff + c * 32 + quad * 8];

  const f32x4 vzero = {0.f, 0.f, 0.f, 0.f};
  f32x4 o[4][8];
  float l_acc[4] = {0.f, 0.f, 0.f, 0.f};  // row-sum for q-row = lr (per mb)
#pragma unroll
  for (int mb = 0; mb < 4; ++mb)
#pragma unroll
    for (int nb = 0; nb < 8; ++nb) o[mb][nb] = vzero;

  bf16x8 kreg[4], vreg[4];
  auto load_tile = [&](int kt) {
    int kbase = kt * 64;
#pragma unroll
    for (int i = 0; i < 4; ++i) {
      int ch = tid + i * 256;
      kreg[i] = *(const bf16x8*)&K[(size_t)(kbase + (ch >> 4)) * DIM + hoff + (ch & 15) * 8];
      vreg[i] = *(const bf16x8*)&Vt[(size_t)(hoff + (ch >> 3)) * N_TOK + kbase + (ch & 7) * 8];
    }
  };
  load_tile(0);

  for (int kt = 0; kt < NT; ++kt) {
    __syncthreads();  // previous tile's LDS reads complete
#pragma unroll
    for (int i = 0; i < 4; ++i) {
      int ch = tid + i * 256;
      *(bf16x8*)&Ksl[(ch >> 4) * LDK + (ch & 15) * 8] = kreg[i];
      *(bf16x8*)&VTsl[(ch >> 3) * LDV + (ch & 7) * 8] = vreg[i];
    }
    __syncthreads();
    if (kt + 1 < NT) load_tile(kt + 1);  // global->reg prefetch under compute

    // S^T = K @ Q^T : lane holds S[q = mb*16+lr][key = nf*16 + quad*4 + r]
    f32x4 s[4][4];
#pragma unroll
    for (int mb = 0; mb < 4; ++mb)
#pragma unroll
      for (int nf = 0; nf < 4; ++nf) s[mb][nf] = vzero;
#pragma unroll
    for (int nf = 0; nf < 4; ++nf)
#pragma unroll
      for (int c = 0; c < 4; ++c) {
        bf16x8 kf = *(const bf16x8*)&Ksl[(nf * 16 + lr) * LDK + c * 32 + quad * 8];
#pragma unroll
        for (int mb = 0; mb < 4; ++mb) s[mb][nf] = mfma16(kf, qf[mb][c], s[mb][nf]);
      }

    // In-register softmax + redistribution into PV A-fragments.
    // Target word t of pf[mb][ki] (lane quad q) = keys ki*32 + q*8 + {2t,2t+1}
    //   = source lane quad (q&1)*2 + (t>>1), W[2ki + (q>>1)][t&1].
    bf16x8 pf[4][2];
#pragma unroll
    for (int mb = 0; mb < 4; ++mb) {
      unsigned W[4][2];
      float lp = 0.f;
#pragma unroll
      for (int nf = 0; nf < 4; ++nf) {
        float e0 = EXP2(s[mb][nf][0]);
        float e1 = EXP2(s[mb][nf][1]);
        float e2 = EXP2(s[mb][nf][2]);
        float e3 = EXP2(s[mb][nf][3]);
        lp += (e0 + e1) + (e2 + e3);
        W[nf][0] = cvtpk_bf16(e0, e1);
        W[nf][1] = cvtpk_bf16(e2, e3);
      }
      l_acc[mb] += lp;
#pragma unroll
      for (int ki = 0; ki < 2; ++ki) {
        u32x2 a0  = pl32swap(W[2 * ki][0], W[2 * ki + 1][0]);
        u32x2 t02 = pl16swap(a0.x, a0.y);   // (T0, T2)
        u32x2 a1  = pl32swap(W[2 * ki][1], W[2 * ki + 1][1]);
        u32x2 t13 = pl16swap(a1.x, a1.y);   // (T1, T3)
        union { unsigned u[4]; bf16x8 v; } pu;
        pu.u[0] = t02.x; pu.u[1] = t13.x; pu.u[2] = t02.y; pu.u[3] = t13.y;
        pf[mb][ki] = pu.v;
      }
    }

    // O += P @ V  (kf/vf reuse across 4 mb is the LDS-traffic win)
#pragma unroll
    for (int nb = 0; nb < 8; ++nb)
#pragma unroll
      for (int ki = 0; ki < 2; ++ki) {
        bf16x8 vf = *(const bf16x8*)&VTsl[(nb * 16 + lr) * LDV + ki * 32 + quad * 8];
#pragma unroll
        for (int mb = 0; mb < 4; ++mb) o[mb][nb] = mfma16(pf[mb][ki], vf, o[mb][nb]);
      }
  }

  // Row-sums live at q-row = lr; reduce the 4 quad-slices, then transpose
  // to q = quad*4+r via shfl for the store.
#pragma unroll
  for (int mb = 0; mb < 4; ++mb) {
    float t = l_acc[mb];
    t += __shfl_xor(t, 16);
    t += __shfl_xor(t, 32);
    l_acc[mb] = t;  // all lanes: L[mb][lr]
  }
#pragma unroll
  for (int mb = 0; mb < 4; ++mb)
#pragma unroll
    for (int r = 0; r < 4; ++r) {
      float Lr = __shfl(l_acc[mb], quad * 4 + r);  // L for q-row quad*4+r
      float inv = 1.0f / Lr;
      int gq = qw + mb * 16 + quad * 4 + r;
#pragma unroll
      for (int nb = 0; nb < 8; ++nb)
        ctx[(size_t)gq * DIM + hoff + nb * 16 + lr] = f2bf(o[mb][nb][r] * inv);
    }
}

extern "C" void kernel_launch(void* const* d_in, const int* in_sizes, int n_in,
                              void* d_out, int out_size, void* d_ws, size_t ws_size,
                              hipStream_t stream) {
  (void)in_sizes; (void)n_in; (void)out_size; (void)ws_size;
  const float* x  = (const float*)d_in[0];
  const float* Wq = (const float*)d_in[1];
  const float* bq = (const float*)d_in[2];
  const float* Wk = (const float*)d_in[3];
  const float* bk = (const float*)d_in[4];
  const float* Wv = (const float*)d_in[5];
  const float* bv = (const float*)d_in[6];
  const float* Wo = (const float*)d_in[7];
  const float* bo = (const float*)d_in[8];

  const size_t NE = (size_t)N_TOK * DIM;  // 8.4M
  unsigned short* xb  = (unsigned short*)d_ws;      // also reused as ctx later
  unsigned short* Wqb = xb + NE;
  unsigned short* Wkb = Wqb + NW;
  unsigned short* Wvb = Wkb + NW;
  unsigned short* Wob = Wvb + NW;
  unsigned short* Qb  = Wob + NW;
  unsigned short* Kb  = Qb + NE;
  unsigned short* Vtb = Kb + NE;   // total ~100.7 MB

  cvt_bf16<<<4096, 256, 0, stream>>>(x,  xb,  (int)NE);
  cvt_bf16<<<2048, 256, 0, stream>>>(Wq, Wqb, NW);
  cvt_bf16<<<2048, 256, 0, stream>>>(Wk, Wkb, NW);
  cvt_bf16<<<2048, 256, 0, stream>>>(Wv, Wvb, NW);
  cvt_bf16<<<2048, 256, 0, stream>>>(Wo, Wob, NW);

  // flat 256-block grid; XCD chunking + m/n decomp inside the kernel (T1)
  const float qscale = 1.4426950408889634f * 0.08838834764831845f;

  gemm_bf16<0><<<256, 512, 0, stream>>>(xb, Wqb, bq, Qb, qscale);
  gemm_bf16<0><<<256, 512, 0, stream>>>(xb, Wkb, bk, Kb, 1.0f);
  gemm_bf16<2><<<256, 512, 0, stream>>>(xb, Wvb, bv, Vtb, 1.0f);

  unsigned short* ctxb = xb;  // x dead after V projection; reuse
  flash_attn<<<dim3(N_TOK / 256, NH), 256, 0, stream>>>(Qb, Kb, Vtb, ctxb);

  gemm_bf16<1><<<256, 512, 0, stream>>>(ctxb, Wob, bo, (float*)d_out, 1.0f);
}

// Round 8
// 436.271 us; speedup vs baseline: 1.2034x; 1.0153x over previous
//
#include <hip/hip_runtime.h>
#include <stdint.h>

#define N_TOK 4096
#define DIM   2048
#define NH    16
#define HD    128
#define NW    (DIM * DIM)

using bf16x8 = __attribute__((ext_vector_type(8))) short;
using bf16x4 = __attribute__((ext_vector_type(4))) short;
using f32x4  = __attribute__((ext_vector_type(4))) float;
using u32x2  = __attribute__((ext_vector_type(2))) unsigned int;

#if __has_builtin(__builtin_amdgcn_exp2f)
#define EXP2(x) __builtin_amdgcn_exp2f(x)
#else
#define EXP2(x) exp2f(x)
#endif

__device__ inline unsigned short f2bf(float f) {
  union { float f; unsigned u; } v; v.f = f;
  unsigned r = v.u + 0x7FFFu + ((v.u >> 16) & 1u);
  return (unsigned short)(r >> 16);
}
__device__ inline float bf2f(unsigned short u) {
  union { unsigned u; float f; } v; v.u = ((unsigned)u) << 16; return v.f;
}
__device__ inline f32x4 mfma16(bf16x8 a, bf16x8 b, f32x4 c) {
  return __builtin_amdgcn_mfma_f32_16x16x32_bf16(a, b, c, 0, 0, 0);
}
// async global->LDS, 16B per lane; LDS dest = wave-uniform base + lane*16
__device__ inline void gll16(const unsigned short* g, unsigned short* l) {
  __builtin_amdgcn_global_load_lds(
      (const __attribute__((address_space(1))) void*)g,
      (__attribute__((address_space(3))) void*)l, 16, 0, 0);
}
// raw barrier with compiler-only memory fences (no waitcnt emitted)
__device__ inline void wgbar() {
  asm volatile("" ::: "memory");
  __builtin_amdgcn_s_barrier();
  asm volatile("" ::: "memory");
}

// pack two f32 -> one u32 of 2x bf16 (RNE). No builtin on gfx950 (guide T12).
__device__ inline unsigned cvtpk_bf16(float lo, float hi) {
  unsigned r;
  asm("v_cvt_pk_bf16_f32 %0, %1, %2" : "=v"(r) : "v"(lo), "v"(hi));
  return r;
}

// permlane swaps (gfx950). ret.x = {A.lo16/32-groups..}, see call sites.
__device__ inline u32x2 pl32swap(unsigned a, unsigned b) {
#if __has_builtin(__builtin_amdgcn_permlane32_swap)
  return __builtin_amdgcn_permlane32_swap(a, b, false, false);
#else
  int lane = threadIdx.x & 63;
  unsigned as = (unsigned)__shfl_xor((int)a, 32);
  unsigned bs = (unsigned)__shfl_xor((int)b, 32);
  u32x2 r;
  r.x = (lane & 32) ? bs : a;   // {A.lo32, B.lo32}
  r.y = (lane & 32) ? b : as;   // {A.hi32, B.hi32}
  return r;
#endif
}
__device__ inline u32x2 pl16swap(unsigned a, unsigned b) {
#if __has_builtin(__builtin_amdgcn_permlane16_swap)
  return __builtin_amdgcn_permlane16_swap(a, b, false, false);
#else
  int lane = threadIdx.x & 63;
  unsigned as = (unsigned)__shfl_xor((int)a, 16);
  unsigned bs = (unsigned)__shfl_xor((int)b, 16);
  u32x2 r;
  r.x = (lane & 16) ? bs : a;   // {A.g0, B.g0, A.g2, B.g2} (16-lane groups)
  r.y = (lane & 16) ? b : as;   // {A.g1, B.g1, A.g3, B.g3}
  return r;
#endif
}

// fp32 -> bf16 convert, 8 elems/thread
__global__ __launch_bounds__(256)
void cvt_bf16(const float* __restrict__ src, unsigned short* __restrict__ dst, int n) {
  int i = blockIdx.x * 256 + threadIdx.x;
  if (i * 8 >= n) return;
  const float4* s = (const float4*)src + (size_t)i * 2;
  float4 a = s[0], b = s[1];
  bf16x8 o;
  o[0] = (short)f2bf(a.x); o[1] = (short)f2bf(a.y);
  o[2] = (short)f2bf(a.z); o[3] = (short)f2bf(a.w);
  o[4] = (short)f2bf(b.x); o[5] = (short)f2bf(b.y);
  o[6] = (short)f2bf(b.z); o[7] = (short)f2bf(b.w);
  *(bf16x8*)(dst + (size_t)i * 8) = o;
}

// C[4096,2048] = A[4096,2048] @ B[2048,2048]^T (+bias)*scale; all-bf16 inputs.
// 8-phase structure (R6) + T1 chunked XCD swizzle (R7): remap
// nb=(bid&7)*32+(bid>>3) (bijective, 256%8==0), m-major decomp -> each XCD =
// 2 m-rows x 16 n-blocks; shared A = 2 MB (L2-fits).
// Pipeline: 3-deep LDS (144 KB), 2 phases/K-tile, s_waitcnt vmcnt(6) once per
// K-tile (6 loads of tile t+2 stay in flight across barriers), MFMA under
// setprio. T2 swizzle via pre-swizzled GLOBAL source col (rule 21) + XOR'd
// ds_read slot. Hazards: stage(t+2) writes buf[(t+2)%3]=buf[(t-1)%3], last
// read >=2 barriers upstream; vmcnt(6)+barrier orders tile t+1 loads before
// any wave reads them. Epilogue peels last 2 tiles (vmcnt(0)).
// OUT_MODE: 0 = bf16 row-major, 1 = fp32 row-major, 2 = bf16 transposed (Vt)
template<int OUT_MODE>
__global__ __launch_bounds__(512, 2)
void gemm_bf16(const unsigned short* __restrict__ A, const unsigned short* __restrict__ B,
               const float* __restrict__ bias, void* __restrict__ out_, float scale) {
  constexpr int BM = 256, BN = 128, BK = 64;
  constexpr int NKT = DIM / BK;              // 32
  __shared__ unsigned short Asl[3][BM * BK]; // 3 x 32 KB
  __shared__ unsigned short Bsl[3][BN * BK]; // 3 x 16 KB  (total 144 KB)

  const int tid  = threadIdx.x;
  const int lane = tid & 63;
  const int w    = tid >> 6;
  const int wm = w >> 1, wn = w & 1;         // 4M x 2N
  const int lr = lane & 15, quad = lane >> 4;

  // T1 chunked XCD swizzle: contiguous 32-block chunk per XCD, m-major.
  const int bid = blockIdx.x;                // 0..255
  const int nb  = (bid & 7) * 32 + (bid >> 3);
  const int m0  = (nb >> 4) * BM;            // 16 m-blocks
  const int n0  = (nb & 15) * BN;            // 16 n-blocks

  const f32x4 vzero = {0.f, 0.f, 0.f, 0.f};
  f32x4 acc[4][4];
#pragma unroll
  for (int i = 0; i < 4; ++i)
#pragma unroll
    for (int j = 0; j < 4; ++j) acc[i][j] = vzero;

  // staging descriptors: A = 4 chunks/thread, B = 2 chunks/thread (16B each).
  // LDS write linear at ch*16B; global source col pre-swizzled (m173).
  size_t asrc[4]; int aldst[4];
  size_t bsrc[2]; int bldst[2];
#pragma unroll
  for (int i = 0; i < 4; ++i) {
    int ch = tid + i * 512;                  // 0..2047
    int row = ch >> 3, cc = ch & 7;
    int gcc = cc ^ (row & 7);
    asrc[i]  = (size_t)(m0 + row) * DIM + gcc * 8;
    aldst[i] = ch * 8;
  }
#pragma unroll
  for (int i = 0; i < 2; ++i) {
    int ch = tid + i * 512;                  // 0..1023
    int row = ch >> 3, cc = ch & 7;
    int gcc = cc ^ (row & 7);
    bsrc[i]  = (size_t)(n0 + row) * DIM + gcc * 8;
    bldst[i] = ch * 8;
  }
  // half 0: A0, A1, B0 ; half 1: A2, A3, B1  (3 gll16 each)
  auto stage_half = [&](int buf, int k0, int half) {
    int a0 = half * 2;
    gll16(&A[asrc[a0] + k0],     &Asl[buf][aldst[a0]]);
    gll16(&A[asrc[a0 + 1] + k0], &Asl[buf][aldst[a0 + 1]]);
    gll16(&B[bsrc[half] + k0],   &Bsl[buf][bldst[half]]);
  };

  auto lda = [&](int buf, int ks, bf16x8* af) {
#pragma unroll
    for (int mb = 0; mb < 4; ++mb) {
      int row  = wm * 64 + mb * 16 + lr;
      int slot = (ks * 4 + quad) ^ (row & 7);
      af[mb] = *(const bf16x8*)&Asl[buf][row * 64 + slot * 8];
    }
  };
  auto ldb = [&](int buf, int ks, bf16x8* bfv) {
#pragma unroll
    for (int nb2 = 0; nb2 < 4; ++nb2) {
      int row  = wn * 64 + nb2 * 16 + lr;
      int slot = (ks * 4 + quad) ^ (row & 7);
      bfv[nb2] = *(const bf16x8*)&Bsl[buf][row * 64 + slot * 8];
    }
  };
  auto mm = [&](bf16x8* af, bf16x8* bfv) {
    __builtin_amdgcn_s_setprio(1);
#pragma unroll
    for (int mb = 0; mb < 4; ++mb)
#pragma unroll
      for (int nb2 = 0; nb2 < 4; ++nb2)
        acc[mb][nb2] = mfma16(af[mb], bfv[nb2], acc[mb][nb2]);
    __builtin_amdgcn_s_setprio(0);
  };

  // ---- prologue: stage tiles 0 and 1; wait tile 0 (6 in flight stays) ----
  stage_half(0, 0, 0);  stage_half(0, 0, 1);
  stage_half(1, BK, 0); stage_half(1, BK, 1);
  asm volatile("s_waitcnt vmcnt(6)" ::: "memory");
  wgbar();

  // ---- main loop: tiles 0..NKT-3, staging t+2, vmcnt(6) per K-tile ----
  for (int t = 0; t < NKT - 2; ++t) {
    const int buf = t % 3, sb = (t + 2) % 3, sk = (t + 2) * BK;
    bf16x8 af[4], bfv[4];
    // phase 0 (k-slice 0)
    lda(buf, 0, af); ldb(buf, 0, bfv);
    stage_half(sb, sk, 0);
    wgbar();
    mm(af, bfv);
    wgbar();
    // phase 1 (k-slice 1)
    lda(buf, 1, af); ldb(buf, 1, bfv);
    stage_half(sb, sk, 1);
    asm volatile("s_waitcnt vmcnt(6)" ::: "memory");  // tile t+1 landed
    wgbar();
    mm(af, bfv);
    wgbar();
  }
  // ---- epilogue tile NKT-2: no staging; drain tile NKT-1 ----
  {
    const int buf = (NKT - 2) % 3;
    bf16x8 af[4], bfv[4];
    lda(buf, 0, af); ldb(buf, 0, bfv);
    wgbar(); mm(af, bfv); wgbar();
    lda(buf, 1, af); ldb(buf, 1, bfv);
    asm volatile("s_waitcnt vmcnt(0)" ::: "memory");  // tile NKT-1 landed
    wgbar(); mm(af, bfv); wgbar();
  }
  // ---- epilogue tile NKT-1: pure compute ----
  {
    const int buf = (NKT - 1) % 3;
    bf16x8 af[4], bfv[4];
    lda(buf, 0, af); ldb(buf, 0, bfv);
    mm(af, bfv);
    lda(buf, 1, af); ldb(buf, 1, bfv);
    mm(af, bfv);
  }

  // ---- C write ----
#pragma unroll
  for (int mb = 0; mb < 4; ++mb)
#pragma unroll
    for (int nb2 = 0; nb2 < 4; ++nb2) {
      int gn = n0 + wn * 64 + nb2 * 16 + lr;
      int gm_base = m0 + wm * 64 + mb * 16 + quad * 4;
      float bs = bias[gn];
      if constexpr (OUT_MODE == 2) {
        bf16x4 pk;
#pragma unroll
        for (int r = 0; r < 4; ++r) pk[r] = (short)f2bf((acc[mb][nb2][r] + bs) * scale);
        *(bf16x4*)&((unsigned short*)out_)[(size_t)gn * N_TOK + gm_base] = pk;
      } else {
#pragma unroll
        for (int r = 0; r < 4; ++r) {
          float v = (acc[mb][nb2][r] + bs) * scale;
          if constexpr (OUT_MODE == 1)
            ((float*)out_)[(size_t)(gm_base + r) * DIM + gn] = v;
          else
            ((unsigned short*)out_)[(size_t)(gm_base + r) * DIM + gn] = f2bf(v);
        }
      }
    }
}

// Flash attention, no-max softmax (scores bounded; exp2 domain folded into Q).
// R3 structure + head-chunked XCD swizzle (R8): flat 256-block grid remapped
// so XCD x owns heads {2x, 2x+1} completely (h=(bid&7)*2+((bid>>3)&1),
// qb=bid>>4; bijective). Each XCD's 32 blocks then share exactly 2 heads'
// K+V = 4 MB = its L2, and same-head blocks march through K/V tiles in near
// lockstep -> K/V re-reads (~500 MB aggregate) served at L2 not LLC class,
// and attn locality no longer depends on GEMM-side cache state (R7 lesson).
// mb=4 (64 q-rows/wave); swapped QK^T (mfma(K,Q)) -> in-register softmax.
__global__ __launch_bounds__(256, 1)
void flash_attn(const unsigned short* __restrict__ Q,
                const unsigned short* __restrict__ K,
                const unsigned short* __restrict__ Vt,
                unsigned short* __restrict__ ctx) {
  constexpr int LDK = 136;  // K tile row stride (128+8)
  constexpr int LDV = 72;   // Vt tile row stride (64+8)
  constexpr int NT  = N_TOK / 64;
  __shared__ unsigned short Ksl[64 * LDK];
  __shared__ unsigned short VTsl[128 * LDV];

  const int tid  = threadIdx.x;
  const int lane = tid & 63, w = tid >> 6;
  const int lr = lane & 15, quad = lane >> 4;

  // head-chunked XCD swizzle (bijective: bid = qb*16 + b1*8 + x)
  const int bid  = blockIdx.x;                   // 0..255
  const int head = (bid & 7) * 2 + ((bid >> 3) & 1);
  const int qblk = bid >> 4;
  const int hoff = head * HD;
  const int q0   = qblk * 256;
  const int qw   = q0 + w * 64;

  // Q fragments; L2E/sqrt(128) already folded in at projection.
  // Layout [free=lr (q-row)][k=c*32+quad*8] = B-operand of swapped mfma(K,Q).
  bf16x8 qf[4][4];
#pragma unroll
  for (int mb = 0; mb < 4; ++mb)
#pragma unroll
    for (int c = 0; c < 4; ++c)
      qf[mb][c] = *(const bf16x8*)&Q[(size_t)(qw + mb * 16 + lr) * DIM + hoff + c * 32 + quad * 8];

  const f32x4 vzero = {0.f, 0.f, 0.f, 0.f};
  f32x4 o[4][8];
  float l_acc[4] = {0.f, 0.f, 0.f, 0.f};  // row-sum for q-row = lr (per mb)
#pragma unroll
  for (int mb = 0; mb < 4; ++mb)
#pragma unroll
    for (int nb = 0; nb < 8; ++nb) o[mb][nb] = vzero;

  bf16x8 kreg[4], vreg[4];
  auto load_tile = [&](int kt) {
    int kbase = kt * 64;
#pragma unroll
    for (int i = 0; i < 4; ++i) {
      int ch = tid + i * 256;
      kreg[i] = *(const bf16x8*)&K[(size_t)(kbase + (ch >> 4)) * DIM + hoff + (ch & 15) * 8];
      vreg[i] = *(const bf16x8*)&Vt[(size_t)(hoff + (ch >> 3)) * N_TOK + kbase + (ch & 7) * 8];
    }
  };
  load_tile(0);

  for (int kt = 0; kt < NT; ++kt) {
    __syncthreads();  // previous tile's LDS reads complete
#pragma unroll
    for (int i = 0; i < 4; ++i) {
      int ch = tid + i * 256;
      *(bf16x8*)&Ksl[(ch >> 4) * LDK + (ch & 15) * 8] = kreg[i];
      *(bf16x8*)&VTsl[(ch >> 3) * LDV + (ch & 7) * 8] = vreg[i];
    }
    __syncthreads();
    if (kt + 1 < NT) load_tile(kt + 1);  // global->reg prefetch under compute

    // S^T = K @ Q^T : lane holds S[q = mb*16+lr][key = nf*16 + quad*4 + r]
    f32x4 s[4][4];
#pragma unroll
    for (int mb = 0; mb < 4; ++mb)
#pragma unroll
      for (int nf = 0; nf < 4; ++nf) s[mb][nf] = vzero;
#pragma unroll
    for (int nf = 0; nf < 4; ++nf)
#pragma unroll
      for (int c = 0; c < 4; ++c) {
        bf16x8 kf = *(const bf16x8*)&Ksl[(nf * 16 + lr) * LDK + c * 32 + quad * 8];
#pragma unroll
        for (int mb = 0; mb < 4; ++mb) s[mb][nf] = mfma16(kf, qf[mb][c], s[mb][nf]);
      }

    // In-register softmax + redistribution into PV A-fragments.
    // Target word t of pf[mb][ki] (lane quad q) = keys ki*32 + q*8 + {2t,2t+1}
    //   = source lane quad (q&1)*2 + (t>>1), W[2ki + (q>>1)][t&1].
    bf16x8 pf[4][2];
#pragma unroll
    for (int mb = 0; mb < 4; ++mb) {
      unsigned W[4][2];
      float lp = 0.f;
#pragma unroll
      for (int nf = 0; nf < 4; ++nf) {
        float e0 = EXP2(s[mb][nf][0]);
        float e1 = EXP2(s[mb][nf][1]);
        float e2 = EXP2(s[mb][nf][2]);
        float e3 = EXP2(s[mb][nf][3]);
        lp += (e0 + e1) + (e2 + e3);
        W[nf][0] = cvtpk_bf16(e0, e1);
        W[nf][1] = cvtpk_bf16(e2, e3);
      }
      l_acc[mb] += lp;
#pragma unroll
      for (int ki = 0; ki < 2; ++ki) {
        u32x2 a0  = pl32swap(W[2 * ki][0], W[2 * ki + 1][0]);
        u32x2 t02 = pl16swap(a0.x, a0.y);   // (T0, T2)
        u32x2 a1  = pl32swap(W[2 * ki][1], W[2 * ki + 1][1]);
        u32x2 t13 = pl16swap(a1.x, a1.y);   // (T1, T3)
        union { unsigned u[4]; bf16x8 v; } pu;
        pu.u[0] = t02.x; pu.u[1] = t13.x; pu.u[2] = t02.y; pu.u[3] = t13.y;
        pf[mb][ki] = pu.v;
      }
    }

    // O += P @ V  (kf/vf reuse across 4 mb is the LDS-traffic win)
#pragma unroll
    for (int nb = 0; nb < 8; ++nb)
#pragma unroll
      for (int ki = 0; ki < 2; ++ki) {
        bf16x8 vf = *(const bf16x8*)&VTsl[(nb * 16 + lr) * LDV + ki * 32 + quad * 8];
#pragma unroll
        for (int mb = 0; mb < 4; ++mb) o[mb][nb] = mfma16(pf[mb][ki], vf, o[mb][nb]);
      }
  }

  // Row-sums live at q-row = lr; reduce the 4 quad-slices, then transpose
  // to q = quad*4+r via shfl for the store.
#pragma unroll
  for (int mb = 0; mb < 4; ++mb) {
    float t = l_acc[mb];
    t += __shfl_xor(t, 16);
    t += __shfl_xor(t, 32);
    l_acc[mb] = t;  // all lanes: L[mb][lr]
  }
#pragma unroll
  for (int mb = 0; mb < 4; ++mb)
#pragma unroll
    for (int r = 0; r < 4; ++r) {
      float Lr = __shfl(l_acc[mb], quad * 4 + r);  // L for q-row quad*4+r
      float inv = 1.0f / Lr;
      int gq = qw + mb * 16 + quad * 4 + r;
#pragma unroll
      for (int nb = 0; nb < 8; ++nb)
        ctx[(size_t)gq * DIM + hoff + nb * 16 + lr] = f2bf(o[mb][nb][r] * inv);
    }
}

extern "C" void kernel_launch(void* const* d_in, const int* in_sizes, int n_in,
                              void* d_out, int out_size, void* d_ws, size_t ws_size,
                              hipStream_t stream) {
  (void)in_sizes; (void)n_in; (void)out_size; (void)ws_size;
  const float* x  = (const float*)d_in[0];
  const float* Wq = (const float*)d_in[1];
  const float* bq = (const float*)d_in[2];
  const float* Wk = (const float*)d_in[3];
  const float* bk = (const float*)d_in[4];
  const float* Wv = (const float*)d_in[5];
  const float* bv = (const float*)d_in[6];
  const float* Wo = (const float*)d_in[7];
  const float* bo = (const float*)d_in[8];

  const size_t NE = (size_t)N_TOK * DIM;  // 8.4M
  unsigned short* xb  = (unsigned short*)d_ws;      // also reused as ctx later
  unsigned short* Wqb = xb + NE;
  unsigned short* Wkb = Wqb + NW;
  unsigned short* Wvb = Wkb + NW;
  unsigned short* Wob = Wvb + NW;
  unsigned short* Qb  = Wob + NW;
  unsigned short* Kb  = Qb + NE;
  unsigned short* Vtb = Kb + NE;   // total ~100.7 MB

  cvt_bf16<<<4096, 256, 0, stream>>>(x,  xb,  (int)NE);
  cvt_bf16<<<2048, 256, 0, stream>>>(Wq, Wqb, NW);
  cvt_bf16<<<2048, 256, 0, stream>>>(Wk, Wkb, NW);
  cvt_bf16<<<2048, 256, 0, stream>>>(Wv, Wvb, NW);
  cvt_bf16<<<2048, 256, 0, stream>>>(Wo, Wob, NW);

  // flat 256-block grids; XCD chunking + decomp inside the kernels (T1)
  const float qscale = 1.4426950408889634f * 0.08838834764831845f;

  gemm_bf16<0><<<256, 512, 0, stream>>>(xb, Wqb, bq, Qb, qscale);
  gemm_bf16<0><<<256, 512, 0, stream>>>(xb, Wkb, bk, Kb, 1.0f);
  gemm_bf16<2><<<256, 512, 0, stream>>>(xb, Wvb, bv, Vtb, 1.0f);

  unsigned short* ctxb = xb;  // x dead after V projection; reuse
  flash_attn<<<256, 256, 0, stream>>>(Qb, Kb, Vtb, ctxb);

  gemm_bf16<1><<<256, 512, 0, stream>>>(ctxb, Wob, bo, (float*)d_out, 1.0f);
}